// Round 6
// baseline (722.916 us; speedup 1.0000x reference)
//
#include <hip/hip_runtime.h>
#include <math.h>

#define HDIM 256
#define NATT 100
#define NBLK2 1024   // main grid; co-resident by construction (4/CU x 256)

typedef __attribute__((ext_vector_type(8))) short short8v;
typedef __attribute__((ext_vector_type(4))) float f32x4;

static __device__ __forceinline__ unsigned short f2bf(float x) {
    union { float f; unsigned u; } v; v.f = x;
    const unsigned r = v.u + 0x7FFFu + ((v.u >> 16) & 1u);
    return (unsigned short)(r >> 16);
}
static __device__ __forceinline__ float bf2f(unsigned short s) {
    union { float f; unsigned u; } v; v.u = ((unsigned)s) << 16;
    return v.f;
}
static __device__ __forceinline__ float fast_tanh(float x) {
    const float e = __builtin_amdgcn_exp2f(x * 2.885390081777927f);
    return 1.f - 2.f * __builtin_amdgcn_rcpf(e + 1.f);
}
static __device__ __forceinline__ float fast_sigmoid(float x) {
    const float e = __builtin_amdgcn_exp2f(-x * 1.4426950408889634f);
    return __builtin_amdgcn_rcpf(1.f + e);
}

struct Params {
    const float *z_dyn, *z_contex, *z_mc;
    const float *b_at, *W_at2, *b_at2;
    const float *Ws1, *bs1, *Ws2, *bs2, *Ws1C, *bs1C, *Ws2C, *bs2C;
    const float *W2, *b2, *Wd, *W2C, *b2C, *WdC, *W_at;
    const float *W_a, *b_a, *W_i, *b_i, *W_iC, *b_iC, *W_e, *b_e, *W_eC, *b_eC;
    const float *g_M, *be_M, *g_C, *be_C;
    float *wcm, *wcc, *m2m, *m2c, *consts, *stats_acc;
    unsigned int *bar;
    unsigned short *WtH, *WtL, *WcH, *WcL;
    float *out;
    int nscene, ntok;
    float inv_n;
};

// ---------------------------------------------------------------------------
// prep (44 blocks x 256): folded weights + split-bf16 weight planes +
// zero barrier/stats. Kernel boundary guarantees coherent visibility to main.
// ---------------------------------------------------------------------------
__launch_bounds__(256)
__global__ void prep_kernel(Params P)
{
    const int tid = threadIdx.x;
    const int blk = blockIdx.x;
    __shared__ float red[6][4];
    if (blk < 4) {
        const int h = blk*64 + (tid>>2), l = tid&3;
        float a = 0.f;
        for (int k = l*64; k < l*64 + 64; ++k) a += P.Ws2[k] * P.Ws1[k*HDIM + h];
        a += __shfl_xor(a, 1); a += __shfl_xor(a, 2);
        if (l == 0) P.wcm[h] = a;
    } else if (blk < 8) {
        const int h = (blk-4)*64 + (tid>>2), l = tid&3;
        float a = 0.f;
        for (int k = l*64; k < l*64 + 64; ++k) a += P.Ws2C[k] * P.Ws1C[k*HDIM + h];
        a += __shfl_xor(a, 1); a += __shfl_xor(a, 2);
        if (l == 0) P.wcc[h] = a;
    } else if (blk < 16) {
        const int idx = (blk-8)*64 + (tid>>2), l = tid&3;
        const int c = idx >> 8, h = idx & 255;
        float a = 0.f;
        for (int k = l*64; k < l*64 + 64; ++k) a += P.Wd[c*HDIM + k] * P.W2[k*HDIM + h];
        a += __shfl_xor(a, 1); a += __shfl_xor(a, 2);
        if (l == 0) P.m2m[c*HDIM + h] = a;
    } else if (blk < 24) {
        const int idx = (blk-16)*64 + (tid>>2), l = tid&3;
        const int c = idx >> 8, h = idx & 255;
        float a = 0.f;
        for (int k = l*64; k < l*64 + 64; ++k) a += P.WdC[c*HDIM + k] * P.W2C[k*HDIM + h];
        a += __shfl_xor(a, 1); a += __shfl_xor(a, 2);
        if (l == 0) P.m2c[c*HDIM + h] = a;
    } else if (blk == 24) {
        const int k = tid;
        float p[6];
        p[0] = P.Ws2[k]       * P.bs1[k];
        p[1] = P.Ws2C[k]      * P.bs1C[k];
        p[2] = P.Wd[k]        * P.b2[k];
        p[3] = P.Wd[HDIM+k]   * P.b2[k];
        p[4] = P.WdC[k]       * P.b2C[k];
        p[5] = P.WdC[HDIM+k]  * P.b2C[k];
        #pragma unroll
        for (int m = 1; m < 64; m <<= 1) {
            #pragma unroll
            for (int q = 0; q < 6; ++q) p[q] += __shfl_xor(p[q], m);
        }
        if ((tid & 63) == 0) {
            #pragma unroll
            for (int q = 0; q < 6; ++q) red[q][tid>>6] = p[q];
        }
        __syncthreads();
        if (tid == 0) {
            float c0 = P.bs2[0], c1 = P.bs2C[0], c2 = 0, c3 = 0, c4 = 0, c5 = 0;
            for (int q = 0; q < 4; ++q) {
                c0 += red[0][q]; c1 += red[1][q]; c2 += red[2][q];
                c3 += red[3][q]; c4 += red[4][q]; c5 += red[5][q];
            }
            P.consts[0] = c0; P.consts[1] = c1; P.consts[2] = c2;
            P.consts[3] = c3; P.consts[4] = c4; P.consts[5] = c5;
        }
    } else if (blk < 33) {
        // W_at split-bf16, tiled [(n*8+kk)*16 + r16][32]
        const int rbase = (blk - 25) * 14;
        const int h = tid;
        for (int rr = 0; rr < 14; ++rr) {
            const int row = rbase + rr;
            const float v = (row < NATT) ? P.W_at[row*HDIM + h] : 0.f;
            const int n = row >> 4, r16 = row & 15;
            const int kk = h >> 5, kc = h & 31;
            const int idx = ((n*8 + kk)*16 + r16)*32 + kc;
            const unsigned short hi = f2bf(v);
            P.WtH[idx] = hi;
            P.WtL[idx] = f2bf(v - bf2f(hi));
        }
    } else if (blk < 43) {
        const int q = blk - 33;          // m*2 + x
        const int m = q >> 1, x = q & 1;
        const int h = tid;
        const float* W; const float* bias; int type;
        switch (m) {
            case 0:  W = P.W_a;  bias = P.b_a;  type = 0; break;
            case 1:  W = P.W_i;  bias = P.b_i;  type = 1; break;
            case 2:  W = P.W_iC; bias = P.b_iC; type = 2; break;
            case 3:  W = P.W_e;  bias = P.b_e;  type = 0; break;
            default: W = P.W_eC; bias = P.b_eC; type = 2; break;
        }
        float tmp[32];
        #pragma unroll
        for (int k = 0; k < 32; ++k) tmp[k] = 0.f;
        if (type == 0) {                 // x_12: 28 cols
            const float* row = W + h*28 + x*14;
            for (int k = 0; k < 14; ++k) tmp[k] = row[k];
        } else if (type == 1) {          // f_12: [zm, cd] per half
            const float* row = W + h*30 + x*15;
            tmp[14] = row[0];
            for (int k = 0; k < 14; ++k) tmp[k] = row[1+k];
        } else {                         // fc_12: [ct_j ct_i zc_j zc_i v_j v_i]
            const float* row = W + h*30;
            for (int k = 0; k < 12; ++k) tmp[2+k] = row[x*12 + k];
            tmp[15] = row[24 + x];
            tmp[0] = row[26 + x*2];
            tmp[1] = row[27 + x*2];
        }
        tmp[16] = 0.5f * bias[h];
        const int base = (q*HDIM + h)*32;
        for (int k = 0; k < 32; ++k) {
            const unsigned short hi = f2bf(tmp[k]);
            P.WcH[base + k] = hi;
            P.WcL[base + k] = f2bf(tmp[k] - bf2f(hi));
        }
    } else {
        if (tid < 64) P.stats_acc[tid] = 0.f;   // 16 slots x 4
        if (tid == 64) P.bar[0] = 0u;
    }
}

// ---------------------------------------------------------------------------
// main+final: 1024 blocks x 256 thr (4 waves), 2 scenes/block.
// All per-scene state block-local (LDS). Cross-block: ONLY device-scope
// atomics (BN stats + arrive/spin barrier). No plain-data handoff.
// ---------------------------------------------------------------------------
__launch_bounds__(256, 4)
__global__ void main_final_kernel(Params P)
{
    __shared__ float s_in[8][16];
    alignas(16) __shared__ float proj[16][260];   // rows 0..7 J-half, 8..15 I-half
    __shared__ float pm2[2][64];                  // pm[j*8+i] per scene
    __shared__ float pmsum2[2][8];
    __shared__ float ss2[2][64];                  // s  per scene
    __shared__ float sq2[2][64];                  // sC per scene
    __shared__ float y_s[16], y2_s[16];
    __shared__ float um2[2][8][2], uc2[2][8][2];
    __shared__ float stf[4];

    const int tid  = threadIdx.x;
    const int blk  = blockIdx.x;
    const int lane = tid & 63;
    const int lw   = tid >> 6;
    const int lr   = lane & 15;
    const int lq   = lane >> 4;

    const float c0 = P.consts[0], c1 = P.consts[1], c2 = P.consts[2];
    const float c3 = P.consts[3], c4 = P.consts[4], c5 = P.consts[5];

    float b0 = 0.f, b1 = 0.f, b2a = 0.f, b3 = 0.f;   // BN partials (wave 0)

#define PROJECT(MIDX)                                                          \
    {                                                                          \
        const int mb2 = (MIDX)*2*HDIM*32;                                      \
        _Pragma("unroll")                                                      \
        for (int jj = 0; jj < 8; ++jj) {                                       \
            const int job = lw*8 + jj;                                         \
            const int x = job >> 4, t = job & 15;                              \
            const int off = mb2 + ((x*HDIM) + t*16 + lr)*32 + lq*8;            \
            const short8v ah = *(const short8v*)&P.WcH[off];                   \
            const short8v al = *(const short8v*)&P.WcL[off];                   \
            f32x4 d = (f32x4){0.f, 0.f, 0.f, 0.f};                             \
            d = __builtin_amdgcn_mfma_f32_16x16x32_bf16(ah, bfh, d, 0, 0, 0);  \
            d = __builtin_amdgcn_mfma_f32_16x16x32_bf16(al, bfh, d, 0, 0, 0);  \
            d = __builtin_amdgcn_mfma_f32_16x16x32_bf16(ah, bfl, d, 0, 0, 0);  \
            if (lr < 8) *(f32x4*)&proj[x*8 + lr][t*16 + lq*4] = d;             \
        }                                                                      \
    }                                                                          \
    __syncthreads();

    for (int sc = 0; sc < 2; ++sc) {
        const int scene = blk*2 + sc;
        __syncthreads();

        // ---- load scene inputs ----
        if (tid < 128) {
            const int o = tid >> 4, c = tid & 15;
            const int tok = scene*8 + o;
            float v;
            if (c < 2)       v = P.z_dyn[tok*2 + c];
            else if (c < 14) v = P.z_contex[tok*12 + (c-2)];
            else             v = P.z_mc[tok*2 + (c-14)];
            s_in[o][c] = v;
        }
        __syncthreads();

        // feature B-fragment (col=obj=lr, k=lq*8+e; k16 = bias one)
        short8v bfh, bfl;
        #pragma unroll
        for (int e = 0; e < 8; ++e) {
            const int k = lq*8 + e;
            float f = 0.f;
            if (lr < 8) f = (k < 16) ? s_in[lr][k] : (k == 16 ? 1.0f : 0.f);
            const unsigned short h16 = f2bf(f);
            bfh[e] = (short)h16;
            bfl[e] = (short)f2bf(f - bf2f(h16));
        }

        // ======== m=0: W_a -> presents ========
        PROJECT(0)
        {
            const int p = lw*16 + lr;        // this lane's pair (B col = lr)
            const int jA = p & 7, iA = p >> 3;
            f32x4 acc[7];
            #pragma unroll
            for (int n = 0; n < 7; ++n) acc[n] = (f32x4){0.f, 0.f, 0.f, 0.f};

            #pragma unroll 2
            for (int k = 0; k < 8; ++k) {
                const int kb = k*32 + lq*8;
                const float4 vj0 = *(const float4*)&proj[jA][kb];
                const float4 vj1 = *(const float4*)&proj[jA][kb+4];
                const float4 vi0 = *(const float4*)&proj[8+iA][kb];
                const float4 vi1 = *(const float4*)&proj[8+iA][kb+4];
                const float v[8] = {vj0.x+vi0.x, vj0.y+vi0.y, vj0.z+vi0.z, vj0.w+vi0.w,
                                    vj1.x+vi1.x, vj1.y+vi1.y, vj1.z+vi1.z, vj1.w+vi1.w};
                short8v pfh, pfl;
                #pragma unroll
                for (int e = 0; e < 8; ++e) {
                    const float r = fmaxf(v[e], 0.f);
                    const unsigned short h16 = f2bf(r);
                    pfh[e] = (short)h16;
                    pfl[e] = (short)f2bf(r - bf2f(h16));
                }
                #pragma unroll
                for (int n = 0; n < 7; ++n) {
                    const int wo = (n*8 + k)*512 + lr*32 + lq*8;
                    const short8v wh = *(const short8v*)&P.WtH[wo];
                    const short8v wl = *(const short8v*)&P.WtL[wo];
                    acc[n] = __builtin_amdgcn_mfma_f32_16x16x32_bf16(wh, pfh, acc[n], 0, 0, 0);
                    acc[n] = __builtin_amdgcn_mfma_f32_16x16x32_bf16(wl, pfh, acc[n], 0, 0, 0);
                    acc[n] = __builtin_amdgcn_mfma_f32_16x16x32_bf16(wh, pfl, acc[n], 0, 0, 0);
                }
            }
            // epilogue: lane holds D rows a = 16n + lq*4 + r for pair col lr
            float part = 0.f;
            #pragma unroll
            for (int n = 0; n < 7; ++n) {
                #pragma unroll
                for (int r = 0; r < 4; ++r) {
                    const int a = 16*n + lq*4 + r;
                    if (a < NATT)
                        part += P.W_at2[a] * fast_tanh(acc[n][r] + P.b_at[a]);
                }
            }
            part += __shfl_xor(part, 16); part += __shfl_xor(part, 32);
            if (lq == 0) {
                const int ip = p >> 3, jp = p & 7;
                const float pres = fast_sigmoid(part + P.b_at2[0]);
                pm2[sc][jp*8 + ip] = (ip != jp) ? pres : 0.f;
            }
        }
        __syncthreads();
        if (tid < 8) {
            const float4 q0 = *(const float4*)&pm2[sc][tid*8];
            const float4 q1 = *(const float4*)&pm2[sc][tid*8 + 4];
            pmsum2[sc][tid] = q0.x+q0.y+q0.z+q0.w + q1.x+q1.y+q1.z+q1.w;
        }

        const int q   = tid >> 2, l2 = tid & 3;   // pair q = jp*8+ip, 4 lanes
        const int jp2 = q >> 3, ip2 = q & 7;

        // ======== m=1: W_i -> s ========
        PROJECT(1)
        {
            float a = 0.f;
            #pragma unroll
            for (int u = 0; u < 16; ++u) {
                const int h4 = (l2*16 + u) * 4;
                const float4 aj = *(const float4*)&proj[jp2][h4];
                const float4 ai = *(const float4*)&proj[8+ip2][h4];
                const float4 wv = *(const float4*)&P.wcm[h4];
                a += wv.x*fmaxf(aj.x+ai.x, 0.f) + wv.y*fmaxf(aj.y+ai.y, 0.f)
                   + wv.z*fmaxf(aj.z+ai.z, 0.f) + wv.w*fmaxf(aj.w+ai.w, 0.f);
            }
            a += __shfl_xor(a, 1); a += __shfl_xor(a, 2);
            if (l2 == 0) ss2[sc][q] = a + c0;
        }
        __syncthreads();

        // ======== m=2: W_iC -> sC ========
        PROJECT(2)
        {
            float a = 0.f;
            #pragma unroll
            for (int u = 0; u < 16; ++u) {
                const int h4 = (l2*16 + u) * 4;
                const float4 aj = *(const float4*)&proj[jp2][h4];
                const float4 ai = *(const float4*)&proj[8+ip2][h4];
                const float4 wv = *(const float4*)&P.wcc[h4];
                a += wv.x*fmaxf(aj.x+ai.x, 0.f) + wv.y*fmaxf(aj.y+ai.y, 0.f)
                   + wv.z*fmaxf(aj.z+ai.z, 0.f) + wv.w*fmaxf(aj.w+ai.w, 0.f);
            }
            a += __shfl_xor(a, 1); a += __shfl_xor(a, 2);
            if (l2 == 0) sq2[sc][q] = a + c1;
        }
        __syncthreads();

        // BN partials accumulate (wave 0)
        if (tid < 64) {
            const float v1 = ss2[sc][tid], v2 = sq2[sc][tid];
            float a0 = v1, a1 = v1*v1, a2 = v2, a3 = v2*v2;
            #pragma unroll
            for (int m = 1; m < 64; m <<= 1) {
                a0 += __shfl_xor(a0, m); a1 += __shfl_xor(a1, m);
                a2 += __shfl_xor(a2, m); a3 += __shfl_xor(a3, m);
            }
            b0 += a0; b1 += a1; b2a += a2; b3 += a3;
        }

        // ======== m=3: W_e -> pm-weighted m2m dot ========
        PROJECT(3)
        {
            float p0 = 0.f, p1 = 0.f;
            #pragma unroll
            for (int u = 0; u < 16; ++u) {
                const int h4 = (l2*16 + u) * 4;
                const float4 aj = *(const float4*)&proj[jp2][h4];
                const float4 ai = *(const float4*)&proj[8+ip2][h4];
                const float4 m0 = *(const float4*)&P.m2m[h4];
                const float4 m1 = *(const float4*)&P.m2m[HDIM + h4];
                const float e0 = fmaxf(aj.x+ai.x, 0.f), e1 = fmaxf(aj.y+ai.y, 0.f);
                const float e2 = fmaxf(aj.z+ai.z, 0.f), e3 = fmaxf(aj.w+ai.w, 0.f);
                p0 += m0.x*e0 + m0.y*e1 + m0.z*e2 + m0.w*e3;
                p1 += m1.x*e0 + m1.y*e1 + m1.z*e2 + m1.w*e3;
            }
            p0 += __shfl_xor(p0, 1); p0 += __shfl_xor(p0, 2);
            p1 += __shfl_xor(p1, 1); p1 += __shfl_xor(p1, 2);
            const float pmv = pm2[sc][q];
            p0 *= pmv; p1 *= pmv;
            p0 += __shfl_xor(p0, 4); p0 += __shfl_xor(p0, 8); p0 += __shfl_xor(p0, 16);
            p1 += __shfl_xor(p1, 4); p1 += __shfl_xor(p1, 8); p1 += __shfl_xor(p1, 16);
            if ((tid & 31) == 0) {
                y_s[(tid>>5)*2 + 0] = p0;
                y_s[(tid>>5)*2 + 1] = p1;
            }
        }
        __syncthreads();

        // ======== m=4: W_eC -> masked m2c dot ========
        PROJECT(4)
        {
            float p0 = 0.f, p1 = 0.f;
            #pragma unroll
            for (int u = 0; u < 16; ++u) {
                const int h4 = (l2*16 + u) * 4;
                const float4 aj = *(const float4*)&proj[jp2][h4];
                const float4 ai = *(const float4*)&proj[8+ip2][h4];
                const float4 m0 = *(const float4*)&P.m2c[h4];
                const float4 m1 = *(const float4*)&P.m2c[HDIM + h4];
                const float e0 = fmaxf(aj.x+ai.x, 0.f), e1 = fmaxf(aj.y+ai.y, 0.f);
                const float e2 = fmaxf(aj.z+ai.z, 0.f), e3 = fmaxf(aj.w+ai.w, 0.f);
                p0 += m0.x*e0 + m0.y*e1 + m0.z*e2 + m0.w*e3;
                p1 += m1.x*e0 + m1.y*e1 + m1.z*e2 + m1.w*e3;
            }
            p0 += __shfl_xor(p0, 1); p0 += __shfl_xor(p0, 2);
            p1 += __shfl_xor(p1, 1); p1 += __shfl_xor(p1, 2);
            const float mk = (ip2 != jp2) ? 1.f : 0.f;
            p0 *= mk; p1 *= mk;
            p0 += __shfl_xor(p0, 4); p0 += __shfl_xor(p0, 8); p0 += __shfl_xor(p0, 16);
            p1 += __shfl_xor(p1, 4); p1 += __shfl_xor(p1, 8); p1 += __shfl_xor(p1, 16);
            if ((tid & 31) == 0) {
                y2_s[(tid>>5)*2 + 0] = p0;
                y2_s[(tid>>5)*2 + 1] = p1;
            }
        }
        __syncthreads();

        // unit vectors (block-local)
        if (tid < 16) {
            const int type = tid >> 3, j = tid & 7;
            float yy0, yy1;
            if (type == 0) {
                const float ps = pmsum2[sc][j];
                yy0 = y_s[j*2]     + ps*c2;
                yy1 = y_s[j*2 + 1] + ps*c3;
            } else {
                yy0 = y2_s[j*2]     + 7.0f*c4;
                yy1 = y2_s[j*2 + 1] + 7.0f*c5;
            }
            const float nrm = fmaxf(sqrtf(yy0*yy0 + yy1*yy1), 1e-12f);
            if (type == 0) { um2[sc][j][0] = yy0/nrm; um2[sc][j][1] = yy1/nrm; }
            else           { uc2[sc][j][0] = yy0/nrm; uc2[sc][j][1] = yy1/nrm; }
        }
    }
#undef PROJECT

    // ---- cross-block: BN stats via device-scope atomics + arrive/spin ----
    if (tid == 0) {
        float* slot = P.stats_acc + (blk & 15)*4;
        atomicAdd(&slot[0], b0); atomicAdd(&slot[1], b1);
        atomicAdd(&slot[2], b2a); atomicAdd(&slot[3], b3);
        __threadfence();
        __hip_atomic_fetch_add(P.bar, 1u, __ATOMIC_ACQ_REL, __HIP_MEMORY_SCOPE_AGENT);
        while (__hip_atomic_load(P.bar, __ATOMIC_ACQUIRE, __HIP_MEMORY_SCOPE_AGENT) < (unsigned)NBLK2)
            __builtin_amdgcn_s_sleep(8);
    }
    __syncthreads();

    // reduce the 16 slots (atomic loads -> coherent)
    if (tid < 64) {
        float v = __hip_atomic_load(&P.stats_acc[tid], __ATOMIC_RELAXED,
                                    __HIP_MEMORY_SCOPE_AGENT);
        v += __shfl_xor(v, 4); v += __shfl_xor(v, 8);
        v += __shfl_xor(v, 16); v += __shfl_xor(v, 32);
        if (tid < 4) stf[tid] = v;     // tid = component c (slot 0 lane)
    }
    __syncthreads();

    // ---- final: this block's 16 tokens, all inputs block-local ----
    if (tid < 16) {
        float mean = stf[0] * P.inv_n;
        float var  = stf[1] * P.inv_n - mean*mean;
        const float kM = P.g_M[0] / sqrtf(var + 1e-5f);
        const float cM = P.be_M[0] - mean*kM;
        mean = stf[2] * P.inv_n;
        var  = stf[3] * P.inv_n - mean*mean;
        const float kC = P.g_C[0] / sqrtf(var + 1e-5f);
        const float cC = P.be_C[0] - mean*kC;

        const int sc = tid >> 3, j = tid & 7;
        const int t = (blk*2 + sc)*8 + j;
        float sum_m = 0.f, sum_c = 0.f;
        #pragma unroll
        for (int i = 0; i < 8; ++i) {
            const int idx = j*8 + i;
            const float sn = ss2[sc][idx]*kM + cM;
            const float sp = fmaxf(sn, 0.f) + log1pf(expf(-fabsf(sn)));
            sum_m += sp * pm2[sc][idx];
            const float snc = sq2[sc][idx]*kC + cC;
            const float spc = fmaxf(snc, 0.f) + log1pf(expf(-fabsf(snc)));
            sum_c += (i != j) ? spc : 0.f;
        }
        const float m0 = sum_m * um2[sc][j][0], m1 = sum_m * um2[sc][j][1];
        const float q0 = sum_c * uc2[sc][j][0], q1 = sum_c * uc2[sc][j][1];
        float* out = P.out;
        const int ntok = P.ntok;
        *(float2*)&out[t*2]          = make_float2(m0 + q0, m1 + q1);
        *(float2*)&out[ntok*2 + t*2] = make_float2(m0, m1);
        *(float2*)&out[ntok*4 + t*2] = make_float2(q0, q1);
    }
}

extern "C" void kernel_launch(void* const* d_in, const int* in_sizes, int n_in,
                              void* d_out, int out_size, void* d_ws, size_t ws_size,
                              hipStream_t stream) {
    Params P;
    P.z_dyn    = (const float*)d_in[0];
    P.z_contex = (const float*)d_in[1];
    P.z_mc     = (const float*)d_in[2];
    P.W_e   = (const float*)d_in[3];  P.b_e   = (const float*)d_in[4];
    P.W_i   = (const float*)d_in[5];  P.b_i   = (const float*)d_in[6];
    P.W_a   = (const float*)d_in[7];  P.b_a   = (const float*)d_in[8];
    P.W2    = (const float*)d_in[9];  P.b2    = (const float*)d_in[10];
    P.W_at  = (const float*)d_in[11]; P.b_at  = (const float*)d_in[12];
    P.W_at2 = (const float*)d_in[13]; P.b_at2 = (const float*)d_in[14];
    P.Ws1   = (const float*)d_in[15]; P.bs1   = (const float*)d_in[16];
    P.Ws2   = (const float*)d_in[17]; P.bs2   = (const float*)d_in[18];
    P.W_eC  = (const float*)d_in[19]; P.b_eC  = (const float*)d_in[20];
    P.W_iC  = (const float*)d_in[21]; P.b_iC  = (const float*)d_in[22];
    P.W2C   = (const float*)d_in[23]; P.b2C   = (const float*)d_in[24];
    P.Ws1C  = (const float*)d_in[25]; P.bs1C  = (const float*)d_in[26];
    P.Ws2C  = (const float*)d_in[27]; P.bs2C  = (const float*)d_in[28];
    P.g_M   = (const float*)d_in[29]; P.be_M  = (const float*)d_in[30];
    P.g_C   = (const float*)d_in[31]; P.be_C  = (const float*)d_in[32];
    P.Wd    = (const float*)d_in[33];
    P.WdC   = (const float*)d_in[34];

    const int ntok = in_sizes[0] / 2;   // 16384
    const int B = ntok / 8;             // 2048

    float* ws = (float*)d_ws;
    P.wcm    = ws;                       // 256
    P.wcc    = P.wcm + 256;              // 256
    P.m2m    = P.wcc + 256;              // 512
    P.m2c    = P.m2m + 512;              // 512
    P.consts = P.m2c + 512;              // 8
    P.stats_acc = P.consts + 8;          // 64 (16 slots x 4)
    P.bar    = (unsigned int*)(P.stats_acc + 64);   // 4
    unsigned short* WtH = (unsigned short*)((float*)P.bar + 4);
    P.WtH = WtH;                         // 7*8*512 = 28672
    P.WtL = WtH + 7*8*512;
    P.WcH = P.WtL + 7*8*512;             // 10*256*32 = 81920
    P.WcL = P.WcH + 10*HDIM*32;
    P.out = (float*)d_out;
    P.nscene = B;
    P.ntok = ntok;
    P.inv_n = 1.0f / (float)(B*64);

    prep_kernel<<<44, 256, 0, stream>>>(P);
    main_final_kernel<<<NBLK2, 256, 0, stream>>>(P);
}

// Round 7
// 512.478 us; speedup vs baseline: 1.4106x; 1.4106x over previous
//
#include <hip/hip_runtime.h>
#include <math.h>

#define HDIM 256
#define NATT 100
#define NBLK2 1024   // main grid; co-resident (4/CU x 256 CUs); spin barrier relies on this
#define PSTR 272     // proj row stride: 272 mod 32 = 16 -> adjacent rows 16 banks apart

typedef __attribute__((ext_vector_type(8))) short short8v;
typedef __attribute__((ext_vector_type(4))) float f32x4;

static __device__ __forceinline__ unsigned short f2bf(float x) {
    union { float f; unsigned u; } v; v.f = x;
    const unsigned r = v.u + 0x7FFFu + ((v.u >> 16) & 1u);
    return (unsigned short)(r >> 16);
}
static __device__ __forceinline__ float bf2f(unsigned short s) {
    union { float f; unsigned u; } v; v.u = ((unsigned)s) << 16;
    return v.f;
}
static __device__ __forceinline__ float fast_tanh(float x) {
    const float e = __builtin_amdgcn_exp2f(x * 2.885390081777927f);
    return 1.f - 2.f * __builtin_amdgcn_rcpf(e + 1.f);
}
static __device__ __forceinline__ float fast_sigmoid(float x) {
    const float e = __builtin_amdgcn_exp2f(-x * 1.4426950408889634f);
    return __builtin_amdgcn_rcpf(1.f + e);
}

struct Params {
    const float *z_dyn, *z_contex, *z_mc;
    const float *b_at, *W_at2, *b_at2;
    const float *Ws1, *bs1, *Ws2, *bs2, *Ws1C, *bs1C, *Ws2C, *bs2C;
    const float *W2, *b2, *Wd, *W2C, *b2C, *WdC, *W_at;
    const float *W_a, *b_a, *W_i, *b_i, *W_iC, *b_iC, *W_e, *b_e, *W_eC, *b_eC;
    const float *g_M, *be_M, *g_C, *be_C;
    float *wcm, *wcc, *m2m, *m2c, *consts, *stats_acc;
    unsigned int *bar;
    unsigned short *WtH, *WtL, *WcH, *WcL;
    float *out;
    int nscene, ntok;
    float inv_n;
};

// ---------------------------------------------------------------------------
// prep (44 blocks x 256): folded weights + split-bf16 weight planes +
// zero barrier/stats. Kernel boundary guarantees coherent visibility to main.
// ---------------------------------------------------------------------------
__launch_bounds__(256)
__global__ void prep_kernel(Params P)
{
    const int tid = threadIdx.x;
    const int blk = blockIdx.x;
    __shared__ float red[6][4];
    if (blk < 4) {
        const int h = blk*64 + (tid>>2), l = tid&3;
        float a = 0.f;
        for (int k = l*64; k < l*64 + 64; ++k) a += P.Ws2[k] * P.Ws1[k*HDIM + h];
        a += __shfl_xor(a, 1); a += __shfl_xor(a, 2);
        if (l == 0) P.wcm[h] = a;
    } else if (blk < 8) {
        const int h = (blk-4)*64 + (tid>>2), l = tid&3;
        float a = 0.f;
        for (int k = l*64; k < l*64 + 64; ++k) a += P.Ws2C[k] * P.Ws1C[k*HDIM + h];
        a += __shfl_xor(a, 1); a += __shfl_xor(a, 2);
        if (l == 0) P.wcc[h] = a;
    } else if (blk < 16) {
        const int idx = (blk-8)*64 + (tid>>2), l = tid&3;
        const int c = idx >> 8, h = idx & 255;
        float a = 0.f;
        for (int k = l*64; k < l*64 + 64; ++k) a += P.Wd[c*HDIM + k] * P.W2[k*HDIM + h];
        a += __shfl_xor(a, 1); a += __shfl_xor(a, 2);
        if (l == 0) P.m2m[c*HDIM + h] = a;
    } else if (blk < 24) {
        const int idx = (blk-16)*64 + (tid>>2), l = tid&3;
        const int c = idx >> 8, h = idx & 255;
        float a = 0.f;
        for (int k = l*64; k < l*64 + 64; ++k) a += P.WdC[c*HDIM + k] * P.W2C[k*HDIM + h];
        a += __shfl_xor(a, 1); a += __shfl_xor(a, 2);
        if (l == 0) P.m2c[c*HDIM + h] = a;
    } else if (blk == 24) {
        const int k = tid;
        float p[6];
        p[0] = P.Ws2[k]       * P.bs1[k];
        p[1] = P.Ws2C[k]      * P.bs1C[k];
        p[2] = P.Wd[k]        * P.b2[k];
        p[3] = P.Wd[HDIM+k]   * P.b2[k];
        p[4] = P.WdC[k]       * P.b2C[k];
        p[5] = P.WdC[HDIM+k]  * P.b2C[k];
        #pragma unroll
        for (int m = 1; m < 64; m <<= 1) {
            #pragma unroll
            for (int q = 0; q < 6; ++q) p[q] += __shfl_xor(p[q], m);
        }
        if ((tid & 63) == 0) {
            #pragma unroll
            for (int q = 0; q < 6; ++q) red[q][tid>>6] = p[q];
        }
        __syncthreads();
        if (tid == 0) {
            float c0 = P.bs2[0], c1 = P.bs2C[0], c2 = 0, c3 = 0, c4 = 0, c5 = 0;
            for (int q = 0; q < 4; ++q) {
                c0 += red[0][q]; c1 += red[1][q]; c2 += red[2][q];
                c3 += red[3][q]; c4 += red[4][q]; c5 += red[5][q];
            }
            P.consts[0] = c0; P.consts[1] = c1; P.consts[2] = c2;
            P.consts[3] = c3; P.consts[4] = c4; P.consts[5] = c5;
        }
    } else if (blk < 33) {
        // W_at split-bf16, tiled [(n*8+kk)*16 + r16][32]
        const int rbase = (blk - 25) * 14;
        const int h = tid;
        for (int rr = 0; rr < 14; ++rr) {
            const int row = rbase + rr;
            const float v = (row < NATT) ? P.W_at[row*HDIM + h] : 0.f;
            const int n = row >> 4, r16 = row & 15;
            const int kk = h >> 5, kc = h & 31;
            const int idx = ((n*8 + kk)*16 + r16)*32 + kc;
            const unsigned short hi = f2bf(v);
            P.WtH[idx] = hi;
            P.WtL[idx] = f2bf(v - bf2f(hi));
        }
    } else if (blk < 43) {
        const int q = blk - 33;          // m*2 + x
        const int m = q >> 1, x = q & 1;
        const int h = tid;
        const float* W; const float* bias; int type;
        switch (m) {
            case 0:  W = P.W_a;  bias = P.b_a;  type = 0; break;
            case 1:  W = P.W_i;  bias = P.b_i;  type = 1; break;
            case 2:  W = P.W_iC; bias = P.b_iC; type = 2; break;
            case 3:  W = P.W_e;  bias = P.b_e;  type = 0; break;
            default: W = P.W_eC; bias = P.b_eC; type = 2; break;
        }
        float tmp[32];
        #pragma unroll
        for (int k = 0; k < 32; ++k) tmp[k] = 0.f;
        if (type == 0) {                 // x_12: 28 cols
            const float* row = W + h*28 + x*14;
            for (int k = 0; k < 14; ++k) tmp[k] = row[k];
        } else if (type == 1) {          // f_12: [zm, cd] per half
            const float* row = W + h*30 + x*15;
            tmp[14] = row[0];
            for (int k = 0; k < 14; ++k) tmp[k] = row[1+k];
        } else {                         // fc_12: [ct_j ct_i zc_j zc_i v_j v_i]
            const float* row = W + h*30;
            for (int k = 0; k < 12; ++k) tmp[2+k] = row[x*12 + k];
            tmp[15] = row[24 + x];
            tmp[0] = row[26 + x*2];
            tmp[1] = row[27 + x*2];
        }
        tmp[16] = 0.5f * bias[h];
        const int base = (q*HDIM + h)*32;
        for (int k = 0; k < 32; ++k) {
            const unsigned short hi = f2bf(tmp[k]);
            P.WcH[base + k] = hi;
            P.WcL[base + k] = f2bf(tmp[k] - bf2f(hi));
        }
    } else {
        if (tid < 64) P.stats_acc[tid] = 0.f;   // 16 slots x 4
        if (tid == 64) P.bar[0] = 0u;
    }
}

// ---------------------------------------------------------------------------
// main+final: 1024 blocks x 256 thr (4 waves), 2 scenes/block.
// All per-scene state block-local (LDS). Cross-block: ONLY device-scope
// atomics (BN stats + arrive/spin barrier, throttled polling).
// ---------------------------------------------------------------------------
__launch_bounds__(256, 4)
__global__ void main_final_kernel(Params P)
{
    __shared__ float s_in[8][16];
    alignas(16) __shared__ float proj[16][PSTR];  // rows 0..7 J-half, 8..15 I-half
    __shared__ float pm2[2][64];                  // pm[j*8+i] per scene
    __shared__ float pmsum2[2][8];
    __shared__ float ss2[2][64];                  // s  per scene
    __shared__ float sq2[2][64];                  // sC per scene
    __shared__ float y_s[16], y2_s[16];
    __shared__ float um2[2][8][2], uc2[2][8][2];
    __shared__ float stf[4];

    const int tid  = threadIdx.x;
    const int blk  = blockIdx.x;
    const int lane = tid & 63;
    const int lw   = tid >> 6;
    const int lr   = lane & 15;
    const int lq   = lane >> 4;

    const float c0 = P.consts[0], c1 = P.consts[1], c2 = P.consts[2];
    const float c3 = P.consts[3], c4 = P.consts[4], c5 = P.consts[5];

    float b0 = 0.f, b1 = 0.f, b2a = 0.f, b3 = 0.f;   // BN partials (wave 0)

#define PROJECT(MIDX)                                                          \
    {                                                                          \
        const int mb2 = (MIDX)*2*HDIM*32;                                      \
        _Pragma("unroll")                                                      \
        for (int jj = 0; jj < 8; ++jj) {                                       \
            const int job = lw*8 + jj;                                         \
            const int x = job >> 4, t = job & 15;                              \
            const int off = mb2 + ((x*HDIM) + t*16 + lr)*32 + lq*8;            \
            const short8v ah = *(const short8v*)&P.WcH[off];                   \
            const short8v al = *(const short8v*)&P.WcL[off];                   \
            f32x4 d = (f32x4){0.f, 0.f, 0.f, 0.f};                             \
            d = __builtin_amdgcn_mfma_f32_16x16x32_bf16(ah, bfh, d, 0, 0, 0);  \
            d = __builtin_amdgcn_mfma_f32_16x16x32_bf16(al, bfh, d, 0, 0, 0);  \
            d = __builtin_amdgcn_mfma_f32_16x16x32_bf16(ah, bfl, d, 0, 0, 0);  \
            if (lr < 8) *(f32x4*)&proj[x*8 + lr][t*16 + lq*4] = d;             \
        }                                                                      \
    }                                                                          \
    __syncthreads();

    for (int sc = 0; sc < 2; ++sc) {
        const int scene = blk*2 + sc;
        __syncthreads();

        // ---- load scene inputs ----
        if (tid < 128) {
            const int o = tid >> 4, c = tid & 15;
            const int tok = scene*8 + o;
            float v;
            if (c < 2)       v = P.z_dyn[tok*2 + c];
            else if (c < 14) v = P.z_contex[tok*12 + (c-2)];
            else             v = P.z_mc[tok*2 + (c-14)];
            s_in[o][c] = v;
        }
        __syncthreads();

        // feature B-fragment (col=obj=lr, k=lq*8+e; k16 = bias one)
        short8v bfh, bfl;
        #pragma unroll
        for (int e = 0; e < 8; ++e) {
            const int k = lq*8 + e;
            float f = 0.f;
            if (lr < 8) f = (k < 16) ? s_in[lr][k] : (k == 16 ? 1.0f : 0.f);
            const unsigned short h16 = f2bf(f);
            bfh[e] = (short)h16;
            bfl[e] = (short)f2bf(f - bf2f(h16));
        }

        // ======== m=0: W_a -> presents ========
        PROJECT(0)
        {
            const int p = lw*16 + lr;        // this lane's pair (B col = lr)
            const int jA = p & 7, iA = p >> 3;
            f32x4 acc[7];
            #pragma unroll
            for (int n = 0; n < 7; ++n) acc[n] = (f32x4){0.f, 0.f, 0.f, 0.f};

            #pragma unroll 2
            for (int k = 0; k < 8; ++k) {
                const int kb = k*32 + lq*8;
                const float4 vj0 = *(const float4*)&proj[jA][kb];
                const float4 vj1 = *(const float4*)&proj[jA][kb+4];
                const float4 vi0 = *(const float4*)&proj[8+iA][kb];
                const float4 vi1 = *(const float4*)&proj[8+iA][kb+4];
                const float v[8] = {vj0.x+vi0.x, vj0.y+vi0.y, vj0.z+vi0.z, vj0.w+vi0.w,
                                    vj1.x+vi1.x, vj1.y+vi1.y, vj1.z+vi1.z, vj1.w+vi1.w};
                short8v pfh, pfl;
                #pragma unroll
                for (int e = 0; e < 8; ++e) {
                    const float r = fmaxf(v[e], 0.f);
                    const unsigned short h16 = f2bf(r);
                    pfh[e] = (short)h16;
                    pfl[e] = (short)f2bf(r - bf2f(h16));
                }
                #pragma unroll
                for (int n = 0; n < 7; ++n) {
                    const int wo = (n*8 + k)*512 + lr*32 + lq*8;
                    const short8v wh = *(const short8v*)&P.WtH[wo];
                    const short8v wl = *(const short8v*)&P.WtL[wo];
                    acc[n] = __builtin_amdgcn_mfma_f32_16x16x32_bf16(wh, pfh, acc[n], 0, 0, 0);
                    acc[n] = __builtin_amdgcn_mfma_f32_16x16x32_bf16(wl, pfh, acc[n], 0, 0, 0);
                    acc[n] = __builtin_amdgcn_mfma_f32_16x16x32_bf16(wh, pfl, acc[n], 0, 0, 0);
                }
            }
            // epilogue: lane holds D rows a = 16n + lq*4 + r for pair col lr
            float part = 0.f;
            #pragma unroll
            for (int n = 0; n < 7; ++n) {
                #pragma unroll
                for (int r = 0; r < 4; ++r) {
                    const int a = 16*n + lq*4 + r;
                    if (a < NATT)
                        part += P.W_at2[a] * fast_tanh(acc[n][r] + P.b_at[a]);
                }
            }
            part += __shfl_xor(part, 16); part += __shfl_xor(part, 32);
            if (lq == 0) {
                const int ip = p >> 3, jp = p & 7;
                const float pres = fast_sigmoid(part + P.b_at2[0]);
                pm2[sc][jp*8 + ip] = (ip != jp) ? pres : 0.f;
            }
        }
        __syncthreads();
        if (tid < 8) {
            const float4 q0 = *(const float4*)&pm2[sc][tid*8];
            const float4 q1 = *(const float4*)&pm2[sc][tid*8 + 4];
            pmsum2[sc][tid] = q0.x+q0.y+q0.z+q0.w + q1.x+q1.y+q1.z+q1.w;
        }

        const int q   = tid >> 2, l2 = tid & 3;   // pair q = jp*8+ip, 4 lanes
        const int jp2 = q >> 3, ip2 = q & 7;

        // ======== m=1: W_i -> s ========
        PROJECT(1)
        {
            float a = 0.f;
            #pragma unroll
            for (int u = 0; u < 16; ++u) {
                const int h4 = u*16 + l2*4;      // l2 lanes 4 floats apart: no bank clash
                const float4 aj = *(const float4*)&proj[jp2][h4];
                const float4 ai = *(const float4*)&proj[8+ip2][h4];
                const float4 wv = *(const float4*)&P.wcm[h4];
                a += wv.x*fmaxf(aj.x+ai.x, 0.f) + wv.y*fmaxf(aj.y+ai.y, 0.f)
                   + wv.z*fmaxf(aj.z+ai.z, 0.f) + wv.w*fmaxf(aj.w+ai.w, 0.f);
            }
            a += __shfl_xor(a, 1); a += __shfl_xor(a, 2);
            if (l2 == 0) ss2[sc][q] = a + c0;
        }
        __syncthreads();

        // ======== m=2: W_iC -> sC ========
        PROJECT(2)
        {
            float a = 0.f;
            #pragma unroll
            for (int u = 0; u < 16; ++u) {
                const int h4 = u*16 + l2*4;
                const float4 aj = *(const float4*)&proj[jp2][h4];
                const float4 ai = *(const float4*)&proj[8+ip2][h4];
                const float4 wv = *(const float4*)&P.wcc[h4];
                a += wv.x*fmaxf(aj.x+ai.x, 0.f) + wv.y*fmaxf(aj.y+ai.y, 0.f)
                   + wv.z*fmaxf(aj.z+ai.z, 0.f) + wv.w*fmaxf(aj.w+ai.w, 0.f);
            }
            a += __shfl_xor(a, 1); a += __shfl_xor(a, 2);
            if (l2 == 0) sq2[sc][q] = a + c1;
        }
        __syncthreads();

        // BN partials accumulate (wave 0)
        if (tid < 64) {
            const float v1 = ss2[sc][tid], v2 = sq2[sc][tid];
            float a0 = v1, a1 = v1*v1, a2 = v2, a3 = v2*v2;
            #pragma unroll
            for (int m = 1; m < 64; m <<= 1) {
                a0 += __shfl_xor(a0, m); a1 += __shfl_xor(a1, m);
                a2 += __shfl_xor(a2, m); a3 += __shfl_xor(a3, m);
            }
            b0 += a0; b1 += a1; b2a += a2; b3 += a3;
        }

        // ======== m=3: W_e -> pm-weighted m2m dot ========
        PROJECT(3)
        {
            float p0 = 0.f, p1 = 0.f;
            #pragma unroll
            for (int u = 0; u < 16; ++u) {
                const int h4 = u*16 + l2*4;
                const float4 aj = *(const float4*)&proj[jp2][h4];
                const float4 ai = *(const float4*)&proj[8+ip2][h4];
                const float4 m0 = *(const float4*)&P.m2m[h4];
                const float4 m1 = *(const float4*)&P.m2m[HDIM + h4];
                const float e0 = fmaxf(aj.x+ai.x, 0.f), e1 = fmaxf(aj.y+ai.y, 0.f);
                const float e2 = fmaxf(aj.z+ai.z, 0.f), e3 = fmaxf(aj.w+ai.w, 0.f);
                p0 += m0.x*e0 + m0.y*e1 + m0.z*e2 + m0.w*e3;
                p1 += m1.x*e0 + m1.y*e1 + m1.z*e2 + m1.w*e3;
            }
            p0 += __shfl_xor(p0, 1); p0 += __shfl_xor(p0, 2);
            p1 += __shfl_xor(p1, 1); p1 += __shfl_xor(p1, 2);
            const float pmv = pm2[sc][q];
            p0 *= pmv; p1 *= pmv;
            p0 += __shfl_xor(p0, 4); p0 += __shfl_xor(p0, 8); p0 += __shfl_xor(p0, 16);
            p1 += __shfl_xor(p1, 4); p1 += __shfl_xor(p1, 8); p1 += __shfl_xor(p1, 16);
            if ((tid & 31) == 0) {
                y_s[(tid>>5)*2 + 0] = p0;
                y_s[(tid>>5)*2 + 1] = p1;
            }
        }
        __syncthreads();

        // ======== m=4: W_eC -> masked m2c dot ========
        PROJECT(4)
        {
            float p0 = 0.f, p1 = 0.f;
            #pragma unroll
            for (int u = 0; u < 16; ++u) {
                const int h4 = u*16 + l2*4;
                const float4 aj = *(const float4*)&proj[jp2][h4];
                const float4 ai = *(const float4*)&proj[8+ip2][h4];
                const float4 m0 = *(const float4*)&P.m2c[h4];
                const float4 m1 = *(const float4*)&P.m2c[HDIM + h4];
                const float e0 = fmaxf(aj.x+ai.x, 0.f), e1 = fmaxf(aj.y+ai.y, 0.f);
                const float e2 = fmaxf(aj.z+ai.z, 0.f), e3 = fmaxf(aj.w+ai.w, 0.f);
                p0 += m0.x*e0 + m0.y*e1 + m0.z*e2 + m0.w*e3;
                p1 += m1.x*e0 + m1.y*e1 + m1.z*e2 + m1.w*e3;
            }
            p0 += __shfl_xor(p0, 1); p0 += __shfl_xor(p0, 2);
            p1 += __shfl_xor(p1, 1); p1 += __shfl_xor(p1, 2);
            const float mk = (ip2 != jp2) ? 1.f : 0.f;
            p0 *= mk; p1 *= mk;
            p0 += __shfl_xor(p0, 4); p0 += __shfl_xor(p0, 8); p0 += __shfl_xor(p0, 16);
            p1 += __shfl_xor(p1, 4); p1 += __shfl_xor(p1, 8); p1 += __shfl_xor(p1, 16);
            if ((tid & 31) == 0) {
                y2_s[(tid>>5)*2 + 0] = p0;
                y2_s[(tid>>5)*2 + 1] = p1;
            }
        }
        __syncthreads();

        // unit vectors (block-local)
        if (tid < 16) {
            const int type = tid >> 3, j = tid & 7;
            float yy0, yy1;
            if (type == 0) {
                const float ps = pmsum2[sc][j];
                yy0 = y_s[j*2]     + ps*c2;
                yy1 = y_s[j*2 + 1] + ps*c3;
            } else {
                yy0 = y2_s[j*2]     + 7.0f*c4;
                yy1 = y2_s[j*2 + 1] + 7.0f*c5;
            }
            const float nrm = fmaxf(sqrtf(yy0*yy0 + yy1*yy1), 1e-12f);
            if (type == 0) { um2[sc][j][0] = yy0/nrm; um2[sc][j][1] = yy1/nrm; }
            else           { uc2[sc][j][0] = yy0/nrm; uc2[sc][j][1] = yy1/nrm; }
        }
    }
#undef PROJECT

    // ---- cross-block: BN stats atomics + THROTTLED arrive/spin barrier ----
    if (tid == 0) {
        float* slot = P.stats_acc + (blk & 15)*4;
        atomicAdd(&slot[0], b0); atomicAdd(&slot[1], b1);
        atomicAdd(&slot[2], b2a); atomicAdd(&slot[3], b3);
        __threadfence();
        __hip_atomic_fetch_add(P.bar, 1u, __ATOMIC_ACQ_REL, __HIP_MEMORY_SCOPE_AGENT);
        // poll ~every 8K cycles (~3.4us): traffic ~1 poll/3.4us/block, not 1/0.2us
        while (__hip_atomic_load(P.bar, __ATOMIC_ACQUIRE, __HIP_MEMORY_SCOPE_AGENT)
               < (unsigned)NBLK2) {
            __builtin_amdgcn_s_sleep(127);
            __builtin_amdgcn_s_sleep(127);
        }
    }
    __syncthreads();

    // reduce the 16 slots (atomic loads -> coherent)
    if (tid < 64) {
        float v = __hip_atomic_load(&P.stats_acc[tid], __ATOMIC_RELAXED,
                                    __HIP_MEMORY_SCOPE_AGENT);
        v += __shfl_xor(v, 4); v += __shfl_xor(v, 8);
        v += __shfl_xor(v, 16); v += __shfl_xor(v, 32);
        if (tid < 4) stf[tid] = v;     // tid = component c (slot 0 lane)
    }
    __syncthreads();

    // ---- final: this block's 16 tokens, all inputs block-local ----
    if (tid < 16) {
        float mean = stf[0] * P.inv_n;
        float var  = stf[1] * P.inv_n - mean*mean;
        const float kM = P.g_M[0] / sqrtf(var + 1e-5f);
        const float cM = P.be_M[0] - mean*kM;
        mean = stf[2] * P.inv_n;
        var  = stf[3] * P.inv_n - mean*mean;
        const float kC = P.g_C[0] / sqrtf(var + 1e-5f);
        const float cC = P.be_C[0] - mean*kC;

        const int sc = tid >> 3, j = tid & 7;
        const int t = (blk*2 + sc)*8 + j;
        float sum_m = 0.f, sum_c = 0.f;
        #pragma unroll
        for (int i = 0; i < 8; ++i) {
            const int idx = j*8 + i;
            const float sn = ss2[sc][idx]*kM + cM;
            const float sp = fmaxf(sn, 0.f) + log1pf(expf(-fabsf(sn)));
            sum_m += sp * pm2[sc][idx];
            const float snc = sq2[sc][idx]*kC + cC;
            const float spc = fmaxf(snc, 0.f) + log1pf(expf(-fabsf(snc)));
            sum_c += (i != j) ? spc : 0.f;
        }
        const float m0 = sum_m * um2[sc][j][0], m1 = sum_m * um2[sc][j][1];
        const float q0 = sum_c * uc2[sc][j][0], q1 = sum_c * uc2[sc][j][1];
        float* out = P.out;
        const int ntok = P.ntok;
        *(float2*)&out[t*2]          = make_float2(m0 + q0, m1 + q1);
        *(float2*)&out[ntok*2 + t*2] = make_float2(m0, m1);
        *(float2*)&out[ntok*4 + t*2] = make_float2(q0, q1);
    }
}

extern "C" void kernel_launch(void* const* d_in, const int* in_sizes, int n_in,
                              void* d_out, int out_size, void* d_ws, size_t ws_size,
                              hipStream_t stream) {
    Params P;
    P.z_dyn    = (const float*)d_in[0];
    P.z_contex = (const float*)d_in[1];
    P.z_mc     = (const float*)d_in[2];
    P.W_e   = (const float*)d_in[3];  P.b_e   = (const float*)d_in[4];
    P.W_i   = (const float*)d_in[5];  P.b_i   = (const float*)d_in[6];
    P.W_a   = (const float*)d_in[7];  P.b_a   = (const float*)d_in[8];
    P.W2    = (const float*)d_in[9];  P.b2    = (const float*)d_in[10];
    P.W_at  = (const float*)d_in[11]; P.b_at  = (const float*)d_in[12];
    P.W_at2 = (const float*)d_in[13]; P.b_at2 = (const float*)d_in[14];
    P.Ws1   = (const float*)d_in[15]; P.bs1   = (const float*)d_in[16];
    P.Ws2   = (const float*)d_in[17]; P.bs2   = (const float*)d_in[18];
    P.W_eC  = (const float*)d_in[19]; P.b_eC  = (const float*)d_in[20];
    P.W_iC  = (const float*)d_in[21]; P.b_iC  = (const float*)d_in[22];
    P.W2C   = (const float*)d_in[23]; P.b2C   = (const float*)d_in[24];
    P.Ws1C  = (const float*)d_in[25]; P.bs1C  = (const float*)d_in[26];
    P.Ws2C  = (const float*)d_in[27]; P.bs2C  = (const float*)d_in[28];
    P.g_M   = (const float*)d_in[29]; P.be_M  = (const float*)d_in[30];
    P.g_C   = (const float*)d_in[31]; P.be_C  = (const float*)d_in[32];
    P.Wd    = (const float*)d_in[33];
    P.WdC   = (const float*)d_in[34];

    const int ntok = in_sizes[0] / 2;   // 16384
    const int B = ntok / 8;             // 2048

    float* ws = (float*)d_ws;
    P.wcm    = ws;                       // 256
    P.wcc    = P.wcm + 256;              // 256
    P.m2m    = P.wcc + 256;              // 512
    P.m2c    = P.m2m + 512;              // 512
    P.consts = P.m2c + 512;              // 8
    P.stats_acc = P.consts + 8;          // 64 (16 slots x 4)
    P.bar    = (unsigned int*)(P.stats_acc + 64);   // 4
    unsigned short* WtH = (unsigned short*)((float*)P.bar + 4);
    P.WtH = WtH;                         // 7*8*512 = 28672
    P.WtL = WtH + 7*8*512;
    P.WcH = P.WtL + 7*8*512;             // 10*256*32 = 81920
    P.WcL = P.WcH + 10*HDIM*32;
    P.out = (float*)d_out;
    P.nscene = B;
    P.ntok = ntok;
    P.inv_n = 1.0f / (float)(B*64);

    prep_kernel<<<44, 256, 0, stream>>>(P);
    main_final_kernel<<<NBLK2, 256, 0, stream>>>(P);
}

// Round 8
// 469.644 us; speedup vs baseline: 1.5393x; 1.0912x over previous
//
#include <hip/hip_runtime.h>
#include <math.h>

#define HDIM 256
#define NATT 100
#define NBLK2 1024   // main grid; co-resident (4/CU x 256 CUs); spin barrier relies on this
#define PSTR 272     // proj row stride: 272 mod 32 = 16 -> adjacent rows 16 banks apart

typedef __attribute__((ext_vector_type(8))) short short8v;
typedef __attribute__((ext_vector_type(4))) float f32x4;

static __device__ __forceinline__ unsigned short f2bf(float x) {
    union { float f; unsigned u; } v; v.f = x;
    const unsigned r = v.u + 0x7FFFu + ((v.u >> 16) & 1u);
    return (unsigned short)(r >> 16);
}
static __device__ __forceinline__ float bf2f(unsigned short s) {
    union { float f; unsigned u; } v; v.u = ((unsigned)s) << 16;
    return v.f;
}
static __device__ __forceinline__ float fast_tanh(float x) {
    const float e = __builtin_amdgcn_exp2f(x * 2.885390081777927f);
    return 1.f - 2.f * __builtin_amdgcn_rcpf(e + 1.f);
}
static __device__ __forceinline__ float fast_sigmoid(float x) {
    const float e = __builtin_amdgcn_exp2f(-x * 1.4426950408889634f);
    return __builtin_amdgcn_rcpf(1.f + e);
}

struct Params {
    const float *z_dyn, *z_contex, *z_mc;
    const float *b_at, *W_at2, *b_at2;
    const float *Ws1, *bs1, *Ws2, *bs2, *Ws1C, *bs1C, *Ws2C, *bs2C;
    const float *W2, *b2, *Wd, *W2C, *b2C, *WdC, *W_at;
    const float *W_a, *b_a, *W_i, *b_i, *W_iC, *b_iC, *W_e, *b_e, *W_eC, *b_eC;
    const float *g_M, *be_M, *g_C, *be_C;
    float *wcm, *wcc, *m2m, *m2c, *consts, *stats_acc;
    unsigned int *bar;
    unsigned short *WtH, *WtL, *WcH, *WcL;
    float *out;
    int nscene, ntok;
    float inv_n;
};

// ---------------------------------------------------------------------------
// prep (44 blocks x 256): folded weights + split-bf16 weight planes +
// zero barrier/stats. Kernel boundary guarantees coherent visibility to main.
// ---------------------------------------------------------------------------
__launch_bounds__(256)
__global__ void prep_kernel(Params P)
{
    const int tid = threadIdx.x;
    const int blk = blockIdx.x;
    __shared__ float red[6][4];
    if (blk < 4) {
        const int h = blk*64 + (tid>>2), l = tid&3;
        float a = 0.f;
        for (int k = l*64; k < l*64 + 64; ++k) a += P.Ws2[k] * P.Ws1[k*HDIM + h];
        a += __shfl_xor(a, 1); a += __shfl_xor(a, 2);
        if (l == 0) P.wcm[h] = a;
    } else if (blk < 8) {
        const int h = (blk-4)*64 + (tid>>2), l = tid&3;
        float a = 0.f;
        for (int k = l*64; k < l*64 + 64; ++k) a += P.Ws2C[k] * P.Ws1C[k*HDIM + h];
        a += __shfl_xor(a, 1); a += __shfl_xor(a, 2);
        if (l == 0) P.wcc[h] = a;
    } else if (blk < 16) {
        const int idx = (blk-8)*64 + (tid>>2), l = tid&3;
        const int c = idx >> 8, h = idx & 255;
        float a = 0.f;
        for (int k = l*64; k < l*64 + 64; ++k) a += P.Wd[c*HDIM + k] * P.W2[k*HDIM + h];
        a += __shfl_xor(a, 1); a += __shfl_xor(a, 2);
        if (l == 0) P.m2m[c*HDIM + h] = a;
    } else if (blk < 24) {
        const int idx = (blk-16)*64 + (tid>>2), l = tid&3;
        const int c = idx >> 8, h = idx & 255;
        float a = 0.f;
        for (int k = l*64; k < l*64 + 64; ++k) a += P.WdC[c*HDIM + k] * P.W2C[k*HDIM + h];
        a += __shfl_xor(a, 1); a += __shfl_xor(a, 2);
        if (l == 0) P.m2c[c*HDIM + h] = a;
    } else if (blk == 24) {
        const int k = tid;
        float p[6];
        p[0] = P.Ws2[k]       * P.bs1[k];
        p[1] = P.Ws2C[k]      * P.bs1C[k];
        p[2] = P.Wd[k]        * P.b2[k];
        p[3] = P.Wd[HDIM+k]   * P.b2[k];
        p[4] = P.WdC[k]       * P.b2C[k];
        p[5] = P.WdC[HDIM+k]  * P.b2C[k];
        #pragma unroll
        for (int m = 1; m < 64; m <<= 1) {
            #pragma unroll
            for (int q = 0; q < 6; ++q) p[q] += __shfl_xor(p[q], m);
        }
        if ((tid & 63) == 0) {
            #pragma unroll
            for (int q = 0; q < 6; ++q) red[q][tid>>6] = p[q];
        }
        __syncthreads();
        if (tid == 0) {
            float c0 = P.bs2[0], c1 = P.bs2C[0], c2 = 0, c3 = 0, c4 = 0, c5 = 0;
            for (int q = 0; q < 4; ++q) {
                c0 += red[0][q]; c1 += red[1][q]; c2 += red[2][q];
                c3 += red[3][q]; c4 += red[4][q]; c5 += red[5][q];
            }
            P.consts[0] = c0; P.consts[1] = c1; P.consts[2] = c2;
            P.consts[3] = c3; P.consts[4] = c4; P.consts[5] = c5;
        }
    } else if (blk < 33) {
        // W_at split-bf16, tiled [(n*8+kk)*16 + r16][32]
        const int rbase = (blk - 25) * 14;
        const int h = tid;
        for (int rr = 0; rr < 14; ++rr) {
            const int row = rbase + rr;
            const float v = (row < NATT) ? P.W_at[row*HDIM + h] : 0.f;
            const int n = row >> 4, r16 = row & 15;
            const int kk = h >> 5, kc = h & 31;
            const int idx = ((n*8 + kk)*16 + r16)*32 + kc;
            const unsigned short hi = f2bf(v);
            P.WtH[idx] = hi;
            P.WtL[idx] = f2bf(v - bf2f(hi));
        }
    } else if (blk < 43) {
        const int q = blk - 33;          // m*2 + x
        const int m = q >> 1, x = q & 1;
        const int h = tid;
        const float* W; const float* bias; int type;
        switch (m) {
            case 0:  W = P.W_a;  bias = P.b_a;  type = 0; break;
            case 1:  W = P.W_i;  bias = P.b_i;  type = 1; break;
            case 2:  W = P.W_iC; bias = P.b_iC; type = 2; break;
            case 3:  W = P.W_e;  bias = P.b_e;  type = 0; break;
            default: W = P.W_eC; bias = P.b_eC; type = 2; break;
        }
        float tmp[32];
        #pragma unroll
        for (int k = 0; k < 32; ++k) tmp[k] = 0.f;
        if (type == 0) {                 // x_12: 28 cols
            const float* row = W + h*28 + x*14;
            for (int k = 0; k < 14; ++k) tmp[k] = row[k];
        } else if (type == 1) {          // f_12: [zm, cd] per half
            const float* row = W + h*30 + x*15;
            tmp[14] = row[0];
            for (int k = 0; k < 14; ++k) tmp[k] = row[1+k];
        } else {                         // fc_12: [ct_j ct_i zc_j zc_i v_j v_i]
            const float* row = W + h*30;
            for (int k = 0; k < 12; ++k) tmp[2+k] = row[x*12 + k];
            tmp[15] = row[24 + x];
            tmp[0] = row[26 + x*2];
            tmp[1] = row[27 + x*2];
        }
        tmp[16] = 0.5f * bias[h];
        const int base = (q*HDIM + h)*32;
        for (int k = 0; k < 32; ++k) {
            const unsigned short hi = f2bf(tmp[k]);
            P.WcH[base + k] = hi;
            P.WcL[base + k] = f2bf(tmp[k] - bf2f(hi));
        }
    } else {
        if (tid < 64) P.stats_acc[tid] = 0.f;   // 16 slots x 4
        if (tid == 64) P.bar[0] = 0u;
    }
}

// ---------------------------------------------------------------------------
// main+final: 1024 blocks x 256 thr (4 waves), 2 scenes/block.
// All per-scene state block-local (LDS). Cross-block: device-scope atomics.
// Barrier lesson (R7): ACQUIRE polls invalidate the XCD L2 every iteration,
// evicting co-resident blocks' weights -> HBM thrash. Poll RELAXED (coherence-
// point read, NO invalidation), then ONE acquire after the count is reached.
// ---------------------------------------------------------------------------
__launch_bounds__(256, 4)
__global__ void main_final_kernel(Params P)
{
    __shared__ float s_in[8][16];
    alignas(16) __shared__ float proj[16][PSTR];  // rows 0..7 J-half, 8..15 I-half
    __shared__ float pm2[2][64];                  // pm[j*8+i] per scene
    __shared__ float pmsum2[2][8];
    __shared__ float ss2[2][64];                  // s  per scene
    __shared__ float sq2[2][64];                  // sC per scene
    __shared__ float y_s[16], y2_s[16];
    __shared__ float um2[2][8][2], uc2[2][8][2];
    __shared__ float stf[4];

    const int tid  = threadIdx.x;
    const int blk  = blockIdx.x;
    const int lane = tid & 63;
    const int lw   = tid >> 6;
    const int lr   = lane & 15;
    const int lq   = lane >> 4;

    const float c0 = P.consts[0], c1 = P.consts[1], c2 = P.consts[2];
    const float c3 = P.consts[3], c4 = P.consts[4], c5 = P.consts[5];

    float b0 = 0.f, b1 = 0.f, b2a = 0.f, b3 = 0.f;   // BN partials (wave 0)

#define PROJECT(MIDX)                                                          \
    {                                                                          \
        const int mb2 = (MIDX)*2*HDIM*32;                                      \
        _Pragma("unroll")                                                      \
        for (int jj = 0; jj < 8; ++jj) {                                       \
            const int job = lw*8 + jj;                                         \
            const int x = job >> 4, t = job & 15;                              \
            const int off = mb2 + ((x*HDIM) + t*16 + lr)*32 + lq*8;            \
            const short8v ah = *(const short8v*)&P.WcH[off];                   \
            const short8v al = *(const short8v*)&P.WcL[off];                   \
            f32x4 d = (f32x4){0.f, 0.f, 0.f, 0.f};                             \
            d = __builtin_amdgcn_mfma_f32_16x16x32_bf16(ah, bfh, d, 0, 0, 0);  \
            d = __builtin_amdgcn_mfma_f32_16x16x32_bf16(al, bfh, d, 0, 0, 0);  \
            d = __builtin_amdgcn_mfma_f32_16x16x32_bf16(ah, bfl, d, 0, 0, 0);  \
            if (lr < 8) *(f32x4*)&proj[x*8 + lr][t*16 + lq*4] = d;             \
        }                                                                      \
    }                                                                          \
    __syncthreads();

    for (int sc = 0; sc < 2; ++sc) {
        const int scene = blk*2 + sc;
        __syncthreads();

        // ---- load scene inputs ----
        if (tid < 128) {
            const int o = tid >> 4, c = tid & 15;
            const int tok = scene*8 + o;
            float v;
            if (c < 2)       v = P.z_dyn[tok*2 + c];
            else if (c < 14) v = P.z_contex[tok*12 + (c-2)];
            else             v = P.z_mc[tok*2 + (c-14)];
            s_in[o][c] = v;
        }
        __syncthreads();

        // feature B-fragment (col=obj=lr, k=lq*8+e; k16 = bias one)
        short8v bfh, bfl;
        #pragma unroll
        for (int e = 0; e < 8; ++e) {
            const int k = lq*8 + e;
            float f = 0.f;
            if (lr < 8) f = (k < 16) ? s_in[lr][k] : (k == 16 ? 1.0f : 0.f);
            const unsigned short h16 = f2bf(f);
            bfh[e] = (short)h16;
            bfl[e] = (short)f2bf(f - bf2f(h16));
        }

        // ======== m=0: W_a -> presents ========
        PROJECT(0)
        {
            const int p = lw*16 + lr;        // this lane's pair (B col = lr)
            const int jA = p & 7, iA = p >> 3;
            f32x4 acc[7];
            #pragma unroll
            for (int n = 0; n < 7; ++n) acc[n] = (f32x4){0.f, 0.f, 0.f, 0.f};

            #pragma unroll 2
            for (int k = 0; k < 8; ++k) {
                const int kb = k*32 + lq*8;
                const float4 vj0 = *(const float4*)&proj[jA][kb];
                const float4 vj1 = *(const float4*)&proj[jA][kb+4];
                const float4 vi0 = *(const float4*)&proj[8+iA][kb];
                const float4 vi1 = *(const float4*)&proj[8+iA][kb+4];
                const float v[8] = {vj0.x+vi0.x, vj0.y+vi0.y, vj0.z+vi0.z, vj0.w+vi0.w,
                                    vj1.x+vi1.x, vj1.y+vi1.y, vj1.z+vi1.z, vj1.w+vi1.w};
                short8v pfh, pfl;
                #pragma unroll
                for (int e = 0; e < 8; ++e) {
                    const float r = fmaxf(v[e], 0.f);
                    const unsigned short h16 = f2bf(r);
                    pfh[e] = (short)h16;
                    pfl[e] = (short)f2bf(r - bf2f(h16));
                }
                #pragma unroll
                for (int n = 0; n < 7; ++n) {
                    const int wo = (n*8 + k)*512 + lr*32 + lq*8;
                    const short8v wh = *(const short8v*)&P.WtH[wo];
                    const short8v wl = *(const short8v*)&P.WtL[wo];
                    acc[n] = __builtin_amdgcn_mfma_f32_16x16x32_bf16(wh, pfh, acc[n], 0, 0, 0);
                    acc[n] = __builtin_amdgcn_mfma_f32_16x16x32_bf16(wl, pfh, acc[n], 0, 0, 0);
                    acc[n] = __builtin_amdgcn_mfma_f32_16x16x32_bf16(wh, pfl, acc[n], 0, 0, 0);
                }
            }
            // epilogue: lane holds D rows a = 16n + lq*4 + r for pair col lr
            float part = 0.f;
            #pragma unroll
            for (int n = 0; n < 7; ++n) {
                #pragma unroll
                for (int r = 0; r < 4; ++r) {
                    const int a = 16*n + lq*4 + r;
                    if (a < NATT)
                        part += P.W_at2[a] * fast_tanh(acc[n][r] + P.b_at[a]);
                }
            }
            part += __shfl_xor(part, 16); part += __shfl_xor(part, 32);
            if (lq == 0) {
                const int ip = p >> 3, jp = p & 7;
                const float pres = fast_sigmoid(part + P.b_at2[0]);
                pm2[sc][jp*8 + ip] = (ip != jp) ? pres : 0.f;
            }
        }
        __syncthreads();
        if (tid < 8) {
            const float4 q0 = *(const float4*)&pm2[sc][tid*8];
            const float4 q1 = *(const float4*)&pm2[sc][tid*8 + 4];
            pmsum2[sc][tid] = q0.x+q0.y+q0.z+q0.w + q1.x+q1.y+q1.z+q1.w;
        }

        const int q   = tid >> 2, l2 = tid & 3;   // pair q = jp*8+ip, 4 lanes
        const int jp2 = q >> 3, ip2 = q & 7;

        // ======== m=1: W_i -> s ========
        PROJECT(1)
        {
            float a = 0.f;
            #pragma unroll
            for (int u = 0; u < 16; ++u) {
                const int h4 = u*16 + l2*4;      // l2 lanes 4 floats apart: no bank clash
                const float4 aj = *(const float4*)&proj[jp2][h4];
                const float4 ai = *(const float4*)&proj[8+ip2][h4];
                const float4 wv = *(const float4*)&P.wcm[h4];
                a += wv.x*fmaxf(aj.x+ai.x, 0.f) + wv.y*fmaxf(aj.y+ai.y, 0.f)
                   + wv.z*fmaxf(aj.z+ai.z, 0.f) + wv.w*fmaxf(aj.w+ai.w, 0.f);
            }
            a += __shfl_xor(a, 1); a += __shfl_xor(a, 2);
            if (l2 == 0) ss2[sc][q] = a + c0;
        }
        __syncthreads();

        // ======== m=2: W_iC -> sC ========
        PROJECT(2)
        {
            float a = 0.f;
            #pragma unroll
            for (int u = 0; u < 16; ++u) {
                const int h4 = u*16 + l2*4;
                const float4 aj = *(const float4*)&proj[jp2][h4];
                const float4 ai = *(const float4*)&proj[8+ip2][h4];
                const float4 wv = *(const float4*)&P.wcc[h4];
                a += wv.x*fmaxf(aj.x+ai.x, 0.f) + wv.y*fmaxf(aj.y+ai.y, 0.f)
                   + wv.z*fmaxf(aj.z+ai.z, 0.f) + wv.w*fmaxf(aj.w+ai.w, 0.f);
            }
            a += __shfl_xor(a, 1); a += __shfl_xor(a, 2);
            if (l2 == 0) sq2[sc][q] = a + c1;
        }
        __syncthreads();

        // BN partials accumulate (wave 0)
        if (tid < 64) {
            const float v1 = ss2[sc][tid], v2 = sq2[sc][tid];
            float a0 = v1, a1 = v1*v1, a2 = v2, a3 = v2*v2;
            #pragma unroll
            for (int m = 1; m < 64; m <<= 1) {
                a0 += __shfl_xor(a0, m); a1 += __shfl_xor(a1, m);
                a2 += __shfl_xor(a2, m); a3 += __shfl_xor(a3, m);
            }
            b0 += a0; b1 += a1; b2a += a2; b3 += a3;
        }

        // ======== m=3: W_e -> pm-weighted m2m dot ========
        PROJECT(3)
        {
            float p0 = 0.f, p1 = 0.f;
            #pragma unroll
            for (int u = 0; u < 16; ++u) {
                const int h4 = u*16 + l2*4;
                const float4 aj = *(const float4*)&proj[jp2][h4];
                const float4 ai = *(const float4*)&proj[8+ip2][h4];
                const float4 m0 = *(const float4*)&P.m2m[h4];
                const float4 m1 = *(const float4*)&P.m2m[HDIM + h4];
                const float e0 = fmaxf(aj.x+ai.x, 0.f), e1 = fmaxf(aj.y+ai.y, 0.f);
                const float e2 = fmaxf(aj.z+ai.z, 0.f), e3 = fmaxf(aj.w+ai.w, 0.f);
                p0 += m0.x*e0 + m0.y*e1 + m0.z*e2 + m0.w*e3;
                p1 += m1.x*e0 + m1.y*e1 + m1.z*e2 + m1.w*e3;
            }
            p0 += __shfl_xor(p0, 1); p0 += __shfl_xor(p0, 2);
            p1 += __shfl_xor(p1, 1); p1 += __shfl_xor(p1, 2);
            const float pmv = pm2[sc][q];
            p0 *= pmv; p1 *= pmv;
            p0 += __shfl_xor(p0, 4); p0 += __shfl_xor(p0, 8); p0 += __shfl_xor(p0, 16);
            p1 += __shfl_xor(p1, 4); p1 += __shfl_xor(p1, 8); p1 += __shfl_xor(p1, 16);
            if ((tid & 31) == 0) {
                y_s[(tid>>5)*2 + 0] = p0;
                y_s[(tid>>5)*2 + 1] = p1;
            }
        }
        __syncthreads();

        // ======== m=4: W_eC -> masked m2c dot ========
        PROJECT(4)
        {
            float p0 = 0.f, p1 = 0.f;
            #pragma unroll
            for (int u = 0; u < 16; ++u) {
                const int h4 = u*16 + l2*4;
                const float4 aj = *(const float4*)&proj[jp2][h4];
                const float4 ai = *(const float4*)&proj[8+ip2][h4];
                const float4 m0 = *(const float4*)&P.m2c[h4];
                const float4 m1 = *(const float4*)&P.m2c[HDIM + h4];
                const float e0 = fmaxf(aj.x+ai.x, 0.f), e1 = fmaxf(aj.y+ai.y, 0.f);
                const float e2 = fmaxf(aj.z+ai.z, 0.f), e3 = fmaxf(aj.w+ai.w, 0.f);
                p0 += m0.x*e0 + m0.y*e1 + m0.z*e2 + m0.w*e3;
                p1 += m1.x*e0 + m1.y*e1 + m1.z*e2 + m1.w*e3;
            }
            p0 += __shfl_xor(p0, 1); p0 += __shfl_xor(p0, 2);
            p1 += __shfl_xor(p1, 1); p1 += __shfl_xor(p1, 2);
            const float mk = (ip2 != jp2) ? 1.f : 0.f;
            p0 *= mk; p1 *= mk;
            p0 += __shfl_xor(p0, 4); p0 += __shfl_xor(p0, 8); p0 += __shfl_xor(p0, 16);
            p1 += __shfl_xor(p1, 4); p1 += __shfl_xor(p1, 8); p1 += __shfl_xor(p1, 16);
            if ((tid & 31) == 0) {
                y2_s[(tid>>5)*2 + 0] = p0;
                y2_s[(tid>>5)*2 + 1] = p1;
            }
        }
        __syncthreads();

        // unit vectors (block-local)
        if (tid < 16) {
            const int type = tid >> 3, j = tid & 7;
            float yy0, yy1;
            if (type == 0) {
                const float ps = pmsum2[sc][j];
                yy0 = y_s[j*2]     + ps*c2;
                yy1 = y_s[j*2 + 1] + ps*c3;
            } else {
                yy0 = y2_s[j*2]     + 7.0f*c4;
                yy1 = y2_s[j*2 + 1] + 7.0f*c5;
            }
            const float nrm = fmaxf(sqrtf(yy0*yy0 + yy1*yy1), 1e-12f);
            if (type == 0) { um2[sc][j][0] = yy0/nrm; um2[sc][j][1] = yy1/nrm; }
            else           { uc2[sc][j][0] = yy0/nrm; uc2[sc][j][1] = yy1/nrm; }
        }
    }
#undef PROJECT

    // ---- cross-block: BN stats atomics + arrive/spin barrier ----
    // RELAXED polls: coherence-point reads, NO L2 invalidation per poll.
    // Exactly ONE acquire after count reached (R7 lesson: acquire-per-poll
    // evicted the XCD L2 continuously -> weights thrashed to HBM).
    if (tid == 0) {
        float* slot = P.stats_acc + (blk & 15)*4;
        atomicAdd(&slot[0], b0); atomicAdd(&slot[1], b1);
        atomicAdd(&slot[2], b2a); atomicAdd(&slot[3], b3);
        __hip_atomic_fetch_add(P.bar, 1u, __ATOMIC_RELEASE, __HIP_MEMORY_SCOPE_AGENT);
        while (__hip_atomic_load(P.bar, __ATOMIC_RELAXED, __HIP_MEMORY_SCOPE_AGENT)
               < (unsigned)NBLK2) {
            __builtin_amdgcn_s_sleep(32);   // ~0.85us between cheap relaxed polls
        }
        const unsigned vv = __hip_atomic_load(P.bar, __ATOMIC_ACQUIRE,
                                              __HIP_MEMORY_SCOPE_AGENT);
        asm volatile("" :: "v"(vv));        // keep the single acquire live
    }
    __syncthreads();

    // reduce the 16 slots (relaxed agent atomic loads -> coherence point)
    if (tid < 64) {
        float v = __hip_atomic_load(&P.stats_acc[tid], __ATOMIC_RELAXED,
                                    __HIP_MEMORY_SCOPE_AGENT);
        v += __shfl_xor(v, 4); v += __shfl_xor(v, 8);
        v += __shfl_xor(v, 16); v += __shfl_xor(v, 32);
        if (tid < 4) stf[tid] = v;     // tid = component c (slot 0 lane)
    }
    __syncthreads();

    // ---- final: this block's 16 tokens, all inputs block-local ----
    if (tid < 16) {
        float mean = stf[0] * P.inv_n;
        float var  = stf[1] * P.inv_n - mean*mean;
        const float kM = P.g_M[0] / sqrtf(var + 1e-5f);
        const float cM = P.be_M[0] - mean*kM;
        mean = stf[2] * P.inv_n;
        var  = stf[3] * P.inv_n - mean*mean;
        const float kC = P.g_C[0] / sqrtf(var + 1e-5f);
        const float cC = P.be_C[0] - mean*kC;

        const int sc = tid >> 3, j = tid & 7;
        const int t = (blk*2 + sc)*8 + j;
        float sum_m = 0.f, sum_c = 0.f;
        #pragma unroll
        for (int i = 0; i < 8; ++i) {
            const int idx = j*8 + i;
            const float sn = ss2[sc][idx]*kM + cM;
            const float sp = fmaxf(sn, 0.f) + log1pf(expf(-fabsf(sn)));
            sum_m += sp * pm2[sc][idx];
            const float snc = sq2[sc][idx]*kC + cC;
            const float spc = fmaxf(snc, 0.f) + log1pf(expf(-fabsf(snc)));
            sum_c += (i != j) ? spc : 0.f;
        }
        const float m0 = sum_m * um2[sc][j][0], m1 = sum_m * um2[sc][j][1];
        const float q0 = sum_c * uc2[sc][j][0], q1 = sum_c * uc2[sc][j][1];
        float* out = P.out;
        const int ntok = P.ntok;
        *(float2*)&out[t*2]          = make_float2(m0 + q0, m1 + q1);
        *(float2*)&out[ntok*2 + t*2] = make_float2(m0, m1);
        *(float2*)&out[ntok*4 + t*2] = make_float2(q0, q1);
    }
}

extern "C" void kernel_launch(void* const* d_in, const int* in_sizes, int n_in,
                              void* d_out, int out_size, void* d_ws, size_t ws_size,
                              hipStream_t stream) {
    Params P;
    P.z_dyn    = (const float*)d_in[0];
    P.z_contex = (const float*)d_in[1];
    P.z_mc     = (const float*)d_in[2];
    P.W_e   = (const float*)d_in[3];  P.b_e   = (const float*)d_in[4];
    P.W_i   = (const float*)d_in[5];  P.b_i   = (const float*)d_in[6];
    P.W_a   = (const float*)d_in[7];  P.b_a   = (const float*)d_in[8];
    P.W2    = (const float*)d_in[9];  P.b2    = (const float*)d_in[10];
    P.W_at  = (const float*)d_in[11]; P.b_at  = (const float*)d_in[12];
    P.W_at2 = (const float*)d_in[13]; P.b_at2 = (const float*)d_in[14];
    P.Ws1   = (const float*)d_in[15]; P.bs1   = (const float*)d_in[16];
    P.Ws2   = (const float*)d_in[17]; P.bs2   = (const float*)d_in[18];
    P.W_eC  = (const float*)d_in[19]; P.b_eC  = (const float*)d_in[20];
    P.W_iC  = (const float*)d_in[21]; P.b_iC  = (const float*)d_in[22];
    P.W2C   = (const float*)d_in[23]; P.b2C   = (const float*)d_in[24];
    P.Ws1C  = (const float*)d_in[25]; P.bs1C  = (const float*)d_in[26];
    P.Ws2C  = (const float*)d_in[27]; P.bs2C  = (const float*)d_in[28];
    P.g_M   = (const float*)d_in[29]; P.be_M  = (const float*)d_in[30];
    P.g_C   = (const float*)d_in[31]; P.be_C  = (const float*)d_in[32];
    P.Wd    = (const float*)d_in[33];
    P.WdC   = (const float*)d_in[34];

    const int ntok = in_sizes[0] / 2;   // 16384
    const int B = ntok / 8;             // 2048

    float* ws = (float*)d_ws;
    P.wcm    = ws;                       // 256
    P.wcc    = P.wcm + 256;              // 256
    P.m2m    = P.wcc + 256;              // 512
    P.m2c    = P.m2m + 512;              // 512
    P.consts = P.m2c + 512;              // 8
    P.stats_acc = P.consts + 8;          // 64 (16 slots x 4)
    P.bar    = (unsigned int*)(P.stats_acc + 64);   // 4
    unsigned short* WtH = (unsigned short*)((float*)P.bar + 4);
    P.WtH = WtH;                         // 7*8*512 = 28672
    P.WtL = WtH + 7*8*512;
    P.WcH = P.WtL + 7*8*512;             // 10*256*32 = 81920
    P.WcL = P.WcH + 10*HDIM*32;
    P.out = (float*)d_out;
    P.nscene = B;
    P.ntok = ntok;
    P.inv_n = 1.0f / (float)(B*64);

    prep_kernel<<<44, 256, 0, stream>>>(P);
    main_final_kernel<<<NBLK2, 256, 0, stream>>>(P);
}